// Round 1
// baseline (207.578 us; speedup 1.0000x reference)
//
#include <hip/hip_runtime.h>
#include <hip/hip_fp16.h>
#include <cstdint>

// Problem shape
#define B_   256
#define CIN  3
#define HW_  64
#define COUT 64
#define FIN  65536   // 64*32*32
#define FOUT 256

// Workspace layout (float indices)
#define ACC_F    0        // 65536 floats: split-K GEMM accumulator
#define SC_F     65536    // [0] maxabs_x bits, [1] max_h bits, [2] p_sf
#define WSF2_F   65552    // 256: per-row absmax bits (uint) of dense_w
#define CBSF_F   65808    // 64: conv bias_sf
#define CBINT_F  65872    // 64: conv b_int (float-valued)
#define CWINT_F  65936    // 1728: conv w_int (float-valued)
#define H16_BYTE (512*1024)  // f16 h buffer, 33.5 MB

typedef _Float16 half8  __attribute__((ext_vector_type(8)));
typedef _Float16 half4v __attribute__((ext_vector_type(4)));
typedef float    floatx4 __attribute__((ext_vector_type(4)));
typedef unsigned short u16;

__device__ inline float blockMax(float v) {
    #pragma unroll
    for (int off = 32; off; off >>= 1) v = fmaxf(v, __shfl_down(v, off));
    __shared__ float sm[8];
    const int lane = threadIdx.x & 63, w = threadIdx.x >> 6;
    if (lane == 0) sm[w] = v;
    __syncthreads();
    float m = sm[0];
    const int nw = blockDim.x >> 6;
    for (int i = 1; i < nw; i++) m = fmaxf(m, sm[i]);
    return m;
}

// ---- kernel 1: global absmax of x ----
__global__ void k_amax_x(const float* __restrict__ x, unsigned* __restrict__ tgt, int n4) {
    const float4* x4 = (const float4*)x;
    float m = 0.f;
    for (int i = blockIdx.x * blockDim.x + threadIdx.x; i < n4; i += gridDim.x * blockDim.x) {
        float4 v = x4[i];
        m = fmaxf(m, fmaxf(fmaxf(fabsf(v.x), fabsf(v.y)), fmaxf(fabsf(v.z), fabsf(v.w))));
    }
    float bm = blockMax(m);
    if (threadIdx.x == 0) atomicMax(tgt, __float_as_uint(bm));
}

// ---- kernel 2: per-row absmax of dense_w (4 blocks per row) ----
__global__ void k_wamax(const float* __restrict__ dw, unsigned* __restrict__ wabs) {
    const int row = blockIdx.x >> 2;
    const int q   = blockIdx.x & 3;
    const float4* r = (const float4*)(dw + (size_t)row * FIN) + q * 4096;
    float m = 0.f;
    for (int i = threadIdx.x; i < 4096; i += 256) {
        float4 v = r[i];
        m = fmaxf(m, fmaxf(fmaxf(fabsf(v.x), fabsf(v.y)), fmaxf(fabsf(v.z), fabsf(v.w))));
    }
    float bm = blockMax(m);
    if (threadIdx.x == 0) atomicMax(wabs + row, __float_as_uint(bm));
}

// ---- kernel 3: quantize conv weights, compute p_sf / bias scales ----
__global__ void k_qconvw(const float* __restrict__ cw, const float* __restrict__ cb,
                         float* ws) {
    const int o = threadIdx.x;  // 64 threads
    const float maxx = __uint_as_float(((const unsigned*)ws)[SC_F + 0]);
    const float p_sf = fmaxf(maxx, 1e-8f) / 32767.0f;
    if (o == 0) ws[SC_F + 2] = p_sf;
    float wv[27];
    float m = 0.f;
    #pragma unroll
    for (int i = 0; i < 27; i++) { wv[i] = cw[o * 27 + i]; m = fmaxf(m, fabsf(wv[i])); }
    const float sf = fmaxf(m, 1e-8f) / 127.0f;
    #pragma unroll
    for (int i = 0; i < 27; i++) {
        float qv = fminf(127.f, fmaxf(-127.f, rintf(wv[i] / sf)));
        ws[CWINT_F + o * 27 + i] = qv;
    }
    const float bsf = p_sf * sf;
    ws[CBSF_F + o]  = bsf;
    ws[CBINT_F + o] = rintf(cb[o] / bsf);
}

// ---- kernel 4: conv 3x3 s2 p1, relu, f16 store, global max(h) ----
// block = (b, oy-tile of 4 rows); thread bits: [4:0]=ox [5]=oy0 [6]=co-half [7]=oy1
// w stays wave-uniform -> scalar loads -> 1 v_fmac per MAC.
__global__ __launch_bounds__(256) void k_conv(const float* __restrict__ x,
                                              const float* __restrict__ ws,
                                              u16* __restrict__ h16,
                                              unsigned* __restrict__ maxh) {
    const int b   = blockIdx.x >> 3;
    const int oyt = (blockIdx.x & 7) * 4;
    const int t   = threadIdx.x;
    const int ox  = t & 31;
    const int ch  = __builtin_amdgcn_readfirstlane((t >> 6) & 1);  // wave-uniform
    const int oy  = oyt + ((t >> 7) << 1) + ((t >> 5) & 1);
    const float p_sf  = ws[SC_F + 2];
    const float inv_p = 1.0f / p_sf;
    const float* xb = x + (size_t)b * (CIN * HW_ * HW_);

    float xs[27];
    #pragma unroll
    for (int ci = 0; ci < 3; ci++)
        #pragma unroll
        for (int ky = 0; ky < 3; ky++) {
            const int iy = 2 * oy - 1 + ky;
            const bool yok = ((unsigned)iy < 64u);
            #pragma unroll
            for (int kx = 0; kx < 3; kx++) {
                const int ix = 2 * ox - 1 + kx;
                float v = (yok && ((unsigned)ix < 64u)) ? xb[(ci * HW_ + iy) * HW_ + ix] : 0.f;
                float q = rintf(v * inv_p);
                xs[ci * 9 + ky * 3 + kx] = fminf(32767.f, fmaxf(-32767.f, q));
            }
        }

    float acc[32];
    const float* wr = ws + CWINT_F + ch * (32 * 27);  // uniform -> s_load
    #pragma unroll
    for (int c = 0; c < 32; c++) {
        float a = 0.f;
        #pragma unroll
        for (int k = 0; k < 27; k++) a = fmaf(xs[k], wr[c * 27 + k], a);
        acc[c] = a;
    }

    float mx = 0.f;
    const size_t base = (size_t)b * FIN + (size_t)ch * 32 * 1024 + oy * 32 + ox;
    #pragma unroll
    for (int c = 0; c < 32; c++) {
        const int co = ch * 32 + c;
        float h = (acc[c] + ws[CBINT_F + co]) * ws[CBSF_F + co];
        h = fmaxf(h, 0.f);
        mx = fmaxf(mx, h);
        h16[base + (size_t)c * 1024] = __half_as_ushort(__float2half(h));
    }
    float bm = blockMax(mx);
    if (t == 0) atomicMax(maxh, __float_as_uint(bm));
}

// ---- kernel 5: split-K f16 MFMA GEMM, on-the-fly requant of A and B ----
// grid: x = output tile (2x2 of 128x128), y = K slice (64 slices of 1024)
__global__ __launch_bounds__(256) void k_gemm(const u16* __restrict__ h16,
                                              const float* __restrict__ dw,
                                              const float* __restrict__ ws,
                                              float* __restrict__ accb) {
    __shared__ __align__(16) _Float16 As[128][72];
    __shared__ __align__(16) _Float16 Bs[128][72];
    __shared__ float invB[128];

    const int tid = threadIdx.x;
    const int tm  = (blockIdx.x >> 1) * 128;
    const int tn  = (blockIdx.x & 1) * 128;
    const int k0  = blockIdx.y * 1024;

    const float max_h  = __uint_as_float(((const unsigned*)ws)[SC_F + 1]);
    const float p2     = fmaxf(max_h, 1e-8f) / 1023.0f;
    const float inv_p2 = 1.0f / p2;

    if (tid < 128) {
        float am = fmaxf(__uint_as_float(((const unsigned*)ws)[WSF2_F + tn + tid]), 1e-8f);
        invB[tid] = 127.0f / am;
    }

    floatx4 acc[4][4];
    const floatx4 zz = {0.f, 0.f, 0.f, 0.f};
    #pragma unroll
    for (int i = 0; i < 4; i++)
        #pragma unroll
        for (int j = 0; j < 4; j++) acc[i][j] = zz;

    const int wv = tid >> 6, lane = tid & 63;
    const int wm = (wv >> 1) * 64, wn = (wv & 1) * 64;
    const int lm = lane & 15, quad = lane >> 4;

    for (int kk = 0; kk < 16; kk++) {
        __syncthreads();
        // stage A: 128 rows x 64 halves, requant h -> int-valued f16
        #pragma unroll
        for (int r = 0; r < 4; r++) {
            const int i = tid + r * 256;
            const int row = i >> 3, c = i & 7;
            const u16* p = h16 + (size_t)(tm + row) * FIN + k0 + kk * 64 + c * 8;
            half8 hv = *(const half8*)p;
            half8 qv;
            #pragma unroll
            for (int j = 0; j < 8; j++) {
                float f = (float)hv[j];
                qv[j] = (_Float16)fminf(1023.f, rintf(f * inv_p2));
            }
            *(half8*)&As[row][c * 8] = qv;
        }
        // stage B: 128 rows x 64 floats, quantize w -> int-valued f16
        #pragma unroll
        for (int r = 0; r < 8; r++) {
            const int i = tid + r * 256;
            const int row = i >> 4, c = i & 15;
            const float* p = dw + (size_t)(tn + row) * FIN + k0 + kk * 64 + c * 4;
            float4 v = *(const float4*)p;
            const float is = invB[row];
            half4v qv;
            qv[0] = (_Float16)fminf(127.f, fmaxf(-127.f, rintf(v.x * is)));
            qv[1] = (_Float16)fminf(127.f, fmaxf(-127.f, rintf(v.y * is)));
            qv[2] = (_Float16)fminf(127.f, fmaxf(-127.f, rintf(v.z * is)));
            qv[3] = (_Float16)fminf(127.f, fmaxf(-127.f, rintf(v.w * is)));
            *(half4v*)&Bs[row][c * 4] = qv;
        }
        __syncthreads();
        #pragma unroll
        for (int ks = 0; ks < 2; ks++) {
            half8 af[4], bf[4];
            #pragma unroll
            for (int mi = 0; mi < 4; mi++)
                af[mi] = *(const half8*)&As[wm + mi * 16 + lm][ks * 32 + quad * 8];
            #pragma unroll
            for (int ni = 0; ni < 4; ni++)
                bf[ni] = *(const half8*)&Bs[wn + ni * 16 + lm][ks * 32 + quad * 8];
            #pragma unroll
            for (int mi = 0; mi < 4; mi++)
                #pragma unroll
                for (int ni = 0; ni < 4; ni++)
                    acc[mi][ni] = __builtin_amdgcn_mfma_f32_16x16x32_f16(af[mi], bf[ni], acc[mi][ni], 0, 0, 0);
        }
    }

    #pragma unroll
    for (int mi = 0; mi < 4; mi++)
        #pragma unroll
        for (int ni = 0; ni < 4; ni++)
            #pragma unroll
            for (int r = 0; r < 4; r++) {
                const int row = tm + wm + mi * 16 + quad * 4 + r;
                const int col = tn + wn + ni * 16 + lm;
                atomicAdd(accb + row * FOUT + col, acc[mi][ni][r]);
            }
}

// ---- kernel 6: epilogue: +b_int, *bias_sf, relu ----
__global__ void k_epi(const float* __restrict__ accb, const float* __restrict__ db,
                      const float* __restrict__ ws, float* __restrict__ out) {
    const int idx = blockIdx.x * 256 + threadIdx.x;
    const int n = idx & 255;
    const float max_h = __uint_as_float(((const unsigned*)ws)[SC_F + 1]);
    const float p2 = fmaxf(max_h, 1e-8f) / 1023.0f;
    const float am = fmaxf(__uint_as_float(((const unsigned*)ws)[WSF2_F + n]), 1e-8f);
    const float wsf = am / 127.0f;
    const float bsf = p2 * wsf;
    const float bint = rintf(db[n] / bsf);
    out[idx] = fmaxf(0.f, (accb[idx] + bint) * bsf);
}

extern "C" void kernel_launch(void* const* d_in, const int* in_sizes, int n_in,
                              void* d_out, int out_size, void* d_ws, size_t ws_size,
                              hipStream_t stream) {
    (void)in_sizes; (void)n_in; (void)out_size; (void)ws_size;
    const float* x  = (const float*)d_in[0];
    const float* cw = (const float*)d_in[1];
    const float* cb = (const float*)d_in[2];
    const float* dw = (const float*)d_in[3];
    const float* db = (const float*)d_in[4];
    float* out = (float*)d_out;
    float* ws  = (float*)d_ws;
    u16* h16   = (u16*)((char*)d_ws + H16_BYTE);
    float* accb = ws + ACC_F;
    unsigned* scal = (unsigned*)(ws + SC_F);
    unsigned* wabs = (unsigned*)(ws + WSF2_F);

    // zero GEMM accumulator + atomic-max slots + per-row absmax slots
    hipMemsetAsync(d_ws, 0, (size_t)(65536 + 16 + 256) * sizeof(float), stream);

    k_amax_x<<<512, 256, 0, stream>>>(x, scal + 0, (B_ * CIN * HW_ * HW_) / 4);
    k_wamax<<<1024, 256, 0, stream>>>(dw, wabs);
    k_qconvw<<<1, 64, 0, stream>>>(cw, cb, ws);
    k_conv<<<2048, 256, 0, stream>>>(x, ws, h16, scal + 1);
    k_gemm<<<dim3(4, 64), 256, 0, stream>>>(h16, dw, ws, accb);
    k_epi<<<256, 256, 0, stream>>>(accb, db, ws, out);
}